// Round 10
// baseline (96.800 us; speedup 1.0000x reference)
//
#include <hip/hip_runtime.h>

#define B_      2
#define NCH     4
#define DIMX    18
#define NPT     (18*18*18)        /* 5832 */
#define TIL     183               /* j-tiles of 32 */
#define ITIL    184               /* i-tiles incl pad */
#define NPTP    (ITIL*32)         /* 5888 */
#define IBLOCKS 23                /* 8 i-tiles per block (2 per wave) */
#define JSP     11                /* j splits: 23*11*2 = 506 blocks (resident @2/CU) */
#define NB      (IBLOCKS*JSP*B_)  /* 506 */
#define MAXT    17                /* max tiles per j-chunk */
#define FSC     (1.2011224087864498f / 5.0f)   /* sqrt(log2 e)/5 */
#define QPAD    -30000.0f

typedef __attribute__((ext_vector_type(8)))  short short8;
typedef __attribute__((ext_vector_type(16))) float f32x16;
typedef __attribute__((ext_vector_type(4)))  int   int4_;

#define EXP2(x) __builtin_amdgcn_exp2f(x)
#define MFMA32(a, b, c) __builtin_amdgcn_mfma_f32_32x32x16_bf16(a, b, c, 0, 0, 0)

// agent-scope (device-coherent) accesses for cross-block data within one launch
__device__ __forceinline__ void g_store(float* p, float v) {
  __hip_atomic_store(p, v, __ATOMIC_RELAXED, __HIP_MEMORY_SCOPE_AGENT);
}
__device__ __forceinline__ float g_load(const float* p) {
  return __hip_atomic_load(p, __ATOMIC_RELAXED, __HIP_MEMORY_SCOPE_AGENT);
}

__device__ __forceinline__ unsigned short bf16rtn(float f) {
  unsigned u = __float_as_uint(f);
  u += 0x7fffu + ((u >> 16) & 1u);
  return (unsigned short)(u >> 16);
}
__device__ __forceinline__ float bf2f(unsigned short s) {
  return __uint_as_float(((unsigned)s) << 16);
}

__device__ __forceinline__ float blockReduceSum(float v) {
  #pragma unroll
  for (int o = 32; o > 0; o >>= 1) v += __shfl_down(v, o, 64);
  __shared__ float red[4];
  int wid = threadIdx.x >> 6, lane = threadIdx.x & 63;
  if (lane == 0) red[wid] = v;
  __syncthreads();
  v = (threadIdx.x < 4) ? red[threadIdx.x] : 0.0f;
  if (wid == 0) {
    v += __shfl_down(v, 2, 64);
    v += __shfl_down(v, 1, 64);
  }
  __syncthreads();
  return v;  // valid on thread 0
}

__device__ __forceinline__ void feat6(const float* __restrict__ I, int bb, int n,
                                      float f[6], float* q) {
  int x = n / (DIMX * DIMX);
  int rem = n - x * DIMX * DIMX;
  int y = rem / DIMX, zz = rem - y * DIMX;
  f[0] = x * FSC; f[1] = y * FSC; f[2] = zz * FSC;
  f[3] = I[(size_t)(bb * 3 + 0) * NPT + n] * FSC;
  f[4] = I[(size_t)(bb * 3 + 1) * NPT + n] * FSC;
  f[5] = I[(size_t)(bb * 3 + 2) * NPT + n] * FSC;
  *q = -0.5f * (f[0]*f[0] + f[1]*f[1] + f[2]*f[2] + f[3]*f[3] + f[4]*f[4] + f[5]*f[5]);
}

__device__ __forceinline__ void bfeat(const float* __restrict__ I, int bb, int n,
                                      short8* hi, short8* lo) {
  short8 h_ = {0,0,0,0,0,0,0,0}, l_ = {0,0,0,0,0,0,0,0};
  if (n < NPT) {
    float f[6], q;
    feat6(I, bb, n, f, &q);
    float bv[8] = {f[0], f[1], f[2], f[3], f[4], f[5], 1.0f, q};
    #pragma unroll
    for (int e = 0; e < 8; ++e) {
      unsigned short bh = bf16rtn(bv[e]);
      h_[e] = (short)bh;
      l_[e] = (short)bf16rtn(bv[e] - bf2f(bh));
    }
  } else {
    h_[7] = (short)bf16rtn(QPAD);   // pad j row -> w = 0 for real i
  }
  *hi = h_; *lo = l_;
}

__device__ __forceinline__ short8 afeat(const float* __restrict__ I, int bb, int n) {
  short8 a = {0,0,0,0,0,0,0,0};
  if (n < NPT) {
    float f[6], q;
    feat6(I, bb, n, f, &q);
    float av[8] = {f[0], f[1], f[2], f[3], f[4], f[5], q, 1.0f};
    #pragma unroll
    for (int e = 0; e < 8; ++e) a[e] = (short)bf16rtn(av[e]);
  }
  return a;
}

__device__ __forceinline__ float4 softmax4(const float* __restrict__ U, int bb, int n) {
  float u0 = U[(size_t)(bb * NCH + 0) * NPT + n];
  float u1 = U[(size_t)(bb * NCH + 1) * NPT + n];
  float u2 = U[(size_t)(bb * NCH + 2) * NPT + n];
  float u3 = U[(size_t)(bb * NCH + 3) * NPT + n];
  float m = fmaxf(fmaxf(u0, u1), fmaxf(u2, u3));
  float e0 = __expf(u0-m), e1 = __expf(u1-m), e2 = __expf(u2-m), e3 = __expf(u3-m);
  float inv = 1.0f / (e0 + e1 + e2 + e3);
  return make_float4(e0*inv, e1*inv, e2*inv, e3*inv);
}

__device__ __forceinline__ float expsum16(const f32x16 acc) {
  float e[16];
  #pragma unroll
  for (int r = 0; r < 16; ++r) e[r] = EXP2(acc[r]);
  float s8[8];
  #pragma unroll
  for (int r = 0; r < 8; ++r) s8[r] = e[2*r] + e[2*r+1];
  float s4[4];
  #pragma unroll
  for (int r = 0; r < 4; ++r) s4[r] = s8[2*r] + s8[2*r+1];
  return (s4[0] + s4[1]) + (s4[2] + s4[3]);
}

__global__ void init_kernel(unsigned* __restrict__ cnt_) {
  if (threadIdx.x < 2) cnt_[threadIdx.x] = 0;
}

__global__ void __launch_bounds__(256, 2)
fused_kernel(const float* __restrict__ I, const float* __restrict__ U,
             float* __restrict__ part, float* __restrict__ pl,
             unsigned* __restrict__ cnt_, float* __restrict__ out) {
  __shared__ short8 bhl[MAXT * 32 * 2];   /* staged once, reused in both phases */
  __shared__ short8 vt8[MAXT * 4 * 4];
  __shared__ bool isLast;
  int tid = threadIdx.x, wid = tid >> 6, l = tid & 63, h = l >> 5, li = l & 31;
  int bb = blockIdx.z, jc = blockIdx.y, ib = blockIdx.x;
  int t0 = jc * TIL / JSP, t1 = (jc + 1) * TIL / JSP;
  int npts = (t1 - t0) * 32;
  unsigned short* vtp = (unsigned short*)vt8;

  // -------- stage j-tiles (used by BOTH phases) --------
  for (int p = tid; p < npts; p += 256) {
    short8 hi, lo;
    bfeat(I, bb, t0 * 32 + p, &hi, &lo);
    bhl[p * 2]     = hi;
    bhl[p * 2 + 1] = lo;
  }
  int i0 = (ib * 8 + wid) * 32 + li;
  int i1 = i0 + 128;
  short8 b1_0 = afeat(I, bb, i0);
  short8 b1_1 = afeat(I, bb, i1);
  __syncthreads();

  f32x16 z;
  #pragma unroll
  for (int r = 0; r < 16; ++r) z[r] = 0.0f;

  // -------- phase A: s_i partials --------
  {
    float sacc0 = 0.0f, sacc1 = 0.0f;
    for (int t = t0; t < t1; ++t) {
      short8 a = bhl[((t - t0) * 32 + li) * 2 + h];
      f32x16 acc0 = MFMA32(a, b1_0, z);
      f32x16 acc1 = MFMA32(a, b1_1, z);
      sacc0 += expsum16(acc0);
      sacc1 += expsum16(acc1);
    }
    sacc0 += __shfl_xor(sacc0, 32, 64);
    sacc1 += __shfl_xor(sacc1, 32, 64);
    if (h == 0) {
      g_store(&part[((size_t)bb * JSP + jc) * NPTP + i0], sacc0);
      g_store(&part[((size_t)bb * JSP + jc) * NPTP + i1], sacc1);
    }
  }

  // -------- device barrier (lean): arrive + tid0 spin --------
  __syncthreads();                 // all waves' part stores issued
  if (tid == 0) {
    __threadfence();
    __hip_atomic_fetch_add(&cnt_[0], 1u, __ATOMIC_ACQ_REL, __HIP_MEMORY_SCOPE_AGENT);
    while (__hip_atomic_load(&cnt_[0], __ATOMIC_ACQUIRE, __HIP_MEMORY_SCOPE_AGENT) < NB)
      __builtin_amdgcn_s_sleep(2);
  }
  __syncthreads();
  __threadfence();

  // -------- phase B staging: vt from part+U --------
  for (int p = tid; p < npts; p += 256) {
    int j = t0 * 32 + p;
    float4 hv = make_float4(0.f, 0.f, 0.f, 0.f);
    float nrm = 0.0f;
    if (j < NPT) {
      float s = 0.0f;
      #pragma unroll
      for (int k = 0; k < JSP; ++k) s += g_load(&part[((size_t)bb * JSP + k) * NPTP + j]);
      nrm = rsqrtf(s + 1e-20f);
      hv = softmax4(U, bb, j);
    }
    int tt = p >> 5, jj = p & 31;
    int g1 = jj >> 4, r = jj & 15;
    int slot = (g1 * 2 + ((r >> 2) & 1)) * 8 + (r & 3) + 4 * (r >> 3);
    vtp[(tt * 4 + 0) * 32 + slot] = bf16rtn(hv.x * nrm);
    vtp[(tt * 4 + 1) * 32 + slot] = bf16rtn(hv.y * nrm);
    vtp[(tt * 4 + 2) * 32 + slot] = bf16rtn(hv.z * nrm);
    vtp[(tt * 4 + 3) * 32 + slot] = bf16rtn(hv.w * nrm);
  }
  float4 g0 = make_float4(0.f, 0.f, 0.f, 0.f), g1v = g0;
  if (i0 < NPT) {
    float s = 0.0f;
    #pragma unroll
    for (int k = 0; k < JSP; ++k) s += g_load(&part[((size_t)bb * JSP + k) * NPTP + i0]);
    float nrm = rsqrtf(s + 1e-20f);
    float4 hh = softmax4(U, bb, i0);
    g0 = make_float4((1.f-hh.x)*nrm, (1.f-hh.y)*nrm, (1.f-hh.z)*nrm, (1.f-hh.w)*nrm);
  }
  if (i1 < NPT) {
    float s = 0.0f;
    #pragma unroll
    for (int k = 0; k < JSP; ++k) s += g_load(&part[((size_t)bb * JSP + k) * NPTP + i1]);
    float nrm = rsqrtf(s + 1e-20f);
    float4 hh = softmax4(U, bb, i1);
    g1v = make_float4((1.f-hh.x)*nrm, (1.f-hh.y)*nrm, (1.f-hh.z)*nrm, (1.f-hh.w)*nrm);
  }
  __syncthreads();

  // -------- phase B: PV + loss --------
  const short8 zer = {0, 0, 0, 0, 0, 0, 0, 0};
  bool cok = li < 4;
  int cc = cok ? li : 0;
  f32x16 d2_0 = z, d2_1 = z;

  for (int t = t0; t < t1; ++t) {
    int tt = t - t0;
    short8 a = bhl[(tt * 32 + li) * 2 + h];
    short8 vf1 = vt8[(tt * 4 + cc) * 4 + h];
    short8 vf2 = vt8[(tt * 4 + cc) * 4 + 2 + h];
    vf1 = cok ? vf1 : zer;
    vf2 = cok ? vf2 : zer;

    f32x16 acc0 = MFMA32(a, b1_0, z);
    f32x16 acc1 = MFMA32(a, b1_1, z);

    float w0[16], w1[16];
    #pragma unroll
    for (int r = 0; r < 16; ++r) { w0[r] = EXP2(acc0[r]); w1[r] = EXP2(acc1[r]); }
    int p0[8], p1[8];
    #pragma unroll
    for (int r = 0; r < 8; ++r) {
      asm("v_cvt_pk_bf16_f32 %0, %1, %2" : "=v"(p0[r]) : "v"(w0[2*r]), "v"(w0[2*r+1]));
      asm("v_cvt_pk_bf16_f32 %0, %1, %2" : "=v"(p1[r]) : "v"(w1[2*r]), "v"(w1[2*r+1]));
    }
    union { int4_ iv; short8 sv; } u1a, u2a, u1b, u2b;
    u1a.iv = (int4_){p0[0], p0[1], p0[2], p0[3]};
    u2a.iv = (int4_){p0[4], p0[5], p0[6], p0[7]};
    u1b.iv = (int4_){p1[0], p1[1], p1[2], p1[3]};
    u2b.iv = (int4_){p1[4], p1[5], p1[6], p1[7]};

    d2_0 = MFMA32(vf1, u1a.sv, d2_0);
    d2_0 = MFMA32(vf2, u2a.sv, d2_0);
    d2_1 = MFMA32(vf1, u1b.sv, d2_1);
    d2_1 = MFMA32(vf2, u2b.sv, d2_1);
  }

  float loss = d2_0[0] * g0.x + d2_0[1] * g0.y + d2_0[2] * g0.z + d2_0[3] * g0.w
             + d2_1[0] * g1v.x + d2_1[1] * g1v.y + d2_1[2] * g1v.z + d2_1[3] * g1v.w;
  float r = blockReduceSum(loss);

  int blkflat = ((bb * JSP + jc) * IBLOCKS + ib);
  if (tid == 0) {
    g_store(&pl[blkflat], r);
    __threadfence();
    unsigned prev = __hip_atomic_fetch_add(&cnt_[1], 1u, __ATOMIC_ACQ_REL,
                                           __HIP_MEMORY_SCOPE_AGENT);
    isLast = (prev == NB - 1);
  }
  __syncthreads();
  if (isLast) {
    __threadfence();
    float v = 0.0f;
    for (int k = tid; k < NB; k += 256) v += g_load(&pl[k]);
    float rr = blockReduceSum(v);
    if (tid == 0) out[0] = rr;
  }
}

extern "C" void kernel_launch(void* const* d_in, const int* in_sizes, int n_in,
                              void* d_out, int out_size, void* d_ws, size_t ws_size,
                              hipStream_t stream) {
  const float* I = (const float*)d_in[0];
  const float* U = (const float*)d_in[1];
  float* out = (float*)d_out;

  char* w = (char*)d_ws;
  float* part = (float*)w;          w += (size_t)B_ * JSP * NPTP * 4;
  float* pl   = (float*)w;          w += (size_t)NB * 4;
  unsigned* cnt_ = (unsigned*)w;    w += 64;

  init_kernel<<<1, 64, 0, stream>>>(cnt_);
  dim3 grid(IBLOCKS, JSP, B_);
  fused_kernel<<<grid, 256, 0, stream>>>(I, U, part, pl, cnt_, out);
}

// Round 11
// 49.928 us; speedup vs baseline: 1.9388x; 1.9388x over previous
//
#include <hip/hip_runtime.h>

#define B_      2
#define NCH     4
#define DIMX    18
#define NPT     (18*18*18)        /* 5832 */
#define TIL     183               /* j-tiles of 32 */
#define ITIL    184               /* i-tiles incl pad */
#define NPTP    (ITIL*32)         /* 5888 */
#define IBLOCKS 23                /* 8 i-tiles per block (2 per wave) */
#define JSP     16                /* j splits: 23*16*2 = 736 blocks */
#define NB      (IBLOCKS*JSP*B_)  /* 736 */
#define MAXT    12                /* max tiles per j-chunk */
#define FSC     (1.2011224087864498f / 5.0f)   /* sqrt(log2 e)/5 */
#define QPAD    -30000.0f

typedef __attribute__((ext_vector_type(8)))  short short8;
typedef __attribute__((ext_vector_type(4)))  short short4_;
typedef __attribute__((ext_vector_type(16))) float f32x16;
typedef __attribute__((ext_vector_type(4)))  int   int4_;

#define EXP2(x) __builtin_amdgcn_exp2f(x)
#define MFMA32(a, b, c) __builtin_amdgcn_mfma_f32_32x32x16_bf16(a, b, c, 0, 0, 0)

__device__ __forceinline__ unsigned short bf16rtn(float f) {
  unsigned u = __float_as_uint(f);
  u += 0x7fffu + ((u >> 16) & 1u);
  return (unsigned short)(u >> 16);
}
__device__ __forceinline__ float bf2f(unsigned short s) {
  return __uint_as_float(((unsigned)s) << 16);
}

__device__ __forceinline__ float blockReduceSum(float v) {
  #pragma unroll
  for (int o = 32; o > 0; o >>= 1) v += __shfl_down(v, o, 64);
  __shared__ float red[4];
  int wid = threadIdx.x >> 6, lane = threadIdx.x & 63;
  if (lane == 0) red[wid] = v;
  __syncthreads();
  v = (threadIdx.x < 4) ? red[threadIdx.x] : 0.0f;
  if (wid == 0) {
    v += __shfl_down(v, 2, 64);
    v += __shfl_down(v, 1, 64);
  }
  __syncthreads();
  return v;  // valid on thread 0
}

__device__ __forceinline__ void feat6(const float* __restrict__ I, int bb, int n,
                                      float f[6], float* q) {
  int x = n / (DIMX * DIMX);
  int rem = n - x * DIMX * DIMX;
  int y = rem / DIMX, zz = rem - y * DIMX;
  f[0] = x * FSC; f[1] = y * FSC; f[2] = zz * FSC;
  f[3] = I[(size_t)(bb * 3 + 0) * NPT + n] * FSC;
  f[4] = I[(size_t)(bb * 3 + 1) * NPT + n] * FSC;
  f[5] = I[(size_t)(bb * 3 + 2) * NPT + n] * FSC;
  *q = -0.5f * (f[0]*f[0] + f[1]*f[1] + f[2]*f[2] + f[3]*f[3] + f[4]*f[4] + f[5]*f[5]);
}

// j-side (f0..f5, 1, q) hi/lo split; pad -> w=0 sentinel
__device__ __forceinline__ void bfeat(const float* __restrict__ I, int bb, int n,
                                      short8* hi, short8* lo) {
  short8 h_ = {0,0,0,0,0,0,0,0}, l_ = {0,0,0,0,0,0,0,0};
  if (n < NPT) {
    float f[6], q;
    feat6(I, bb, n, f, &q);
    float bv[8] = {f[0], f[1], f[2], f[3], f[4], f[5], 1.0f, q};
    #pragma unroll
    for (int e = 0; e < 8; ++e) {
      unsigned short bh = bf16rtn(bv[e]);
      h_[e] = (short)bh;
      l_[e] = (short)bf16rtn(bv[e] - bf2f(bh));
    }
  } else {
    h_[7] = (short)bf16rtn(QPAD);
  }
  *hi = h_; *lo = l_;
}

// i-side (f0..f5, q, 1) hi only; pad -> 0
__device__ __forceinline__ short8 afeat(const float* __restrict__ I, int bb, int n) {
  short8 a = {0,0,0,0,0,0,0,0};
  if (n < NPT) {
    float f[6], q;
    feat6(I, bb, n, f, &q);
    float av[8] = {f[0], f[1], f[2], f[3], f[4], f[5], q, 1.0f};
    #pragma unroll
    for (int e = 0; e < 8; ++e) a[e] = (short)bf16rtn(av[e]);
  }
  return a;
}

__device__ __forceinline__ float4 softmax4(const float* __restrict__ U, int bb, int n) {
  float u0 = U[(size_t)(bb * NCH + 0) * NPT + n];
  float u1 = U[(size_t)(bb * NCH + 1) * NPT + n];
  float u2 = U[(size_t)(bb * NCH + 2) * NPT + n];
  float u3 = U[(size_t)(bb * NCH + 3) * NPT + n];
  float m = fmaxf(fmaxf(u0, u1), fmaxf(u2, u3));
  float e0 = __expf(u0-m), e1 = __expf(u1-m), e2 = __expf(u2-m), e3 = __expf(u3-m);
  float inv = 1.0f / (e0 + e1 + e2 + e3);
  return make_float4(e0*inv, e1*inv, e2*inv, e3*inv);
}

__device__ __forceinline__ float expsum16(const f32x16 acc) {
  float e[16];
  #pragma unroll
  for (int r = 0; r < 16; ++r) e[r] = EXP2(acc[r]);
  float s8[8];
  #pragma unroll
  for (int r = 0; r < 8; ++r) s8[r] = e[2*r] + e[2*r+1];
  float s4[4];
  #pragma unroll
  for (int r = 0; r < 4; ++r) s4[r] = s8[2*r] + s8[2*r+1];
  return (s4[0] + s4[1]) + (s4[2] + s4[3]);
}

// ---------------- K1: pass1 (prep fused, LDS-staged j) ----------------
__global__ void __launch_bounds__(256) pass1_kernel(const float* __restrict__ I,
                                                    float* __restrict__ part) {
  __shared__ short8 bhl[MAXT * 32 * 2];
  int tid = threadIdx.x, wid = tid >> 6, l = tid & 63, h = l >> 5, li = l & 31;
  int bb = blockIdx.z, jc = blockIdx.y, ib = blockIdx.x;
  int t0 = jc * TIL / JSP, t1 = (jc + 1) * TIL / JSP;
  int npts = (t1 - t0) * 32;

  for (int p = tid; p < npts; p += 256) {
    short8 hi, lo;
    bfeat(I, bb, t0 * 32 + p, &hi, &lo);
    bhl[p * 2]     = hi;
    bhl[p * 2 + 1] = lo;
  }
  int i0 = (ib * 8 + wid) * 32 + li;
  int i1 = i0 + 128;
  short8 b1_0 = afeat(I, bb, i0);
  short8 b1_1 = afeat(I, bb, i1);
  __syncthreads();

  f32x16 z;
  #pragma unroll
  for (int r = 0; r < 16; ++r) z[r] = 0.0f;

  float sacc0 = 0.0f, sacc1 = 0.0f;
  for (int t = t0; t < t1; ++t) {
    short8 a = bhl[((t - t0) * 32 + li) * 2 + h];
    f32x16 acc0 = MFMA32(a, b1_0, z);
    f32x16 acc1 = MFMA32(a, b1_1, z);
    sacc0 += expsum16(acc0);
    sacc1 += expsum16(acc1);
  }
  sacc0 += __shfl_xor(sacc0, 32, 64);
  sacc1 += __shfl_xor(sacc1, 32, 64);
  if (h == 0) {
    part[((size_t)bb * JSP + jc) * NPTP + i0] = sacc0;
    part[((size_t)bb * JSP + jc) * NPTP + i1] = sacc1;
  }
}

// ---------------- K2: finalize (softmax inline) ----------------
__global__ void finalize_kernel(const float* __restrict__ U, const float* __restrict__ part,
                                unsigned short* __restrict__ Vt, float4* __restrict__ G4) {
  int idx = blockIdx.x * 256 + threadIdx.x;
  if (idx >= B_ * NPTP) return;
  int bb = idx / NPTP, ii = idx - bb * NPTP;
  if (ii < NPT) {
    float s = 0.0f;
    #pragma unroll
    for (int k = 0; k < JSP; ++k) s += part[((size_t)bb * JSP + k) * NPTP + ii];
    float nrm = rsqrtf(s + 1e-20f);
    float4 hh = softmax4(U, bb, ii);
    Vt[((size_t)bb * 4 + 0) * NPTP + ii] = bf16rtn(hh.x * nrm);
    Vt[((size_t)bb * 4 + 1) * NPTP + ii] = bf16rtn(hh.y * nrm);
    Vt[((size_t)bb * 4 + 2) * NPTP + ii] = bf16rtn(hh.z * nrm);
    Vt[((size_t)bb * 4 + 3) * NPTP + ii] = bf16rtn(hh.w * nrm);
    G4[idx] = make_float4((1.0f - hh.x) * nrm, (1.0f - hh.y) * nrm,
                          (1.0f - hh.z) * nrm, (1.0f - hh.w) * nrm);
  } else {
    Vt[((size_t)bb * 4 + 0) * NPTP + ii] = 0;
    Vt[((size_t)bb * 4 + 1) * NPTP + ii] = 0;
    Vt[((size_t)bb * 4 + 2) * NPTP + ii] = 0;
    Vt[((size_t)bb * 4 + 3) * NPTP + ii] = 0;
    G4[idx] = make_float4(0.f, 0.f, 0.f, 0.f);
  }
}

__device__ __forceinline__ void ldv(const unsigned short* __restrict__ vrow, int j32,
                                    int h, bool cok, short8* vf1, short8* vf2) {
  const short4_ zer4 = {0, 0, 0, 0};
  short4_ va = cok ? *(const short4_*)(vrow + j32 + 4*h)      : zer4;
  short4_ vb = cok ? *(const short4_*)(vrow + j32 + 8 + 4*h)  : zer4;
  short4_ vc = cok ? *(const short4_*)(vrow + j32 + 16 + 4*h) : zer4;
  short4_ vd = cok ? *(const short4_*)(vrow + j32 + 24 + 4*h) : zer4;
  short8 f1, f2;
  #pragma unroll
  for (int e = 0; e < 4; ++e) {
    f1[e] = va[e]; f1[4 + e] = vb[e];
    f2[e] = vc[e]; f2[4 + e] = vd[e];
  }
  *vf1 = f1; *vf2 = f2;
}

// ---------------- K3: pass2 (prep fused, last-block reduce fused) ----------------
__global__ void __launch_bounds__(256) pass2_kernel(const float* __restrict__ I,
                                                    const unsigned short* __restrict__ Vt,
                                                    const float4* __restrict__ G4,
                                                    float* __restrict__ pl,
                                                    unsigned* __restrict__ cnt_,
                                                    float* __restrict__ out) {
  __shared__ short8 bhl[MAXT * 32 * 2];
  __shared__ bool isLast;
  int tid = threadIdx.x, wid = tid >> 6, l = tid & 63, h = l >> 5, li = l & 31;
  int bb = blockIdx.z, jc = blockIdx.y, ib = blockIdx.x;
  int t0 = jc * TIL / JSP, t1 = (jc + 1) * TIL / JSP;
  int npts = (t1 - t0) * 32;

  for (int p = tid; p < npts; p += 256) {
    short8 hi, lo;
    bfeat(I, bb, t0 * 32 + p, &hi, &lo);
    bhl[p * 2]     = hi;
    bhl[p * 2 + 1] = lo;
  }
  int i0 = (ib * 8 + wid) * 32 + li;
  int i1 = i0 + 128;
  short8 b1_0 = afeat(I, bb, i0);
  short8 b1_1 = afeat(I, bb, i1);
  size_t pbase = (size_t)bb * NPTP;
  float4 g0 = G4[pbase + i0];
  float4 g1v = G4[pbase + i1];
  bool cok = li < 4;
  const unsigned short* vrow = Vt + ((size_t)bb * 4 + (cok ? li : 0)) * NPTP;
  __syncthreads();

  f32x16 z;
  #pragma unroll
  for (int r = 0; r < 16; ++r) z[r] = 0.0f;
  f32x16 d2_0 = z, d2_1 = z;

  for (int t = t0; t < t1; ++t) {
    short8 a = bhl[((t - t0) * 32 + li) * 2 + h];
    short8 vf1, vf2;
    ldv(vrow, t * 32, h, cok, &vf1, &vf2);

    f32x16 acc0 = MFMA32(a, b1_0, z);
    f32x16 acc1 = MFMA32(a, b1_1, z);

    float w0[16], w1[16];
    #pragma unroll
    for (int r = 0; r < 16; ++r) { w0[r] = EXP2(acc0[r]); w1[r] = EXP2(acc1[r]); }
    int p0[8], p1[8];
    #pragma unroll
    for (int r = 0; r < 8; ++r) {
      asm("v_cvt_pk_bf16_f32 %0, %1, %2" : "=v"(p0[r]) : "v"(w0[2*r]), "v"(w0[2*r+1]));
      asm("v_cvt_pk_bf16_f32 %0, %1, %2" : "=v"(p1[r]) : "v"(w1[2*r]), "v"(w1[2*r+1]));
    }
    union { int4_ iv; short8 sv; } u1a, u2a, u1b, u2b;
    u1a.iv = (int4_){p0[0], p0[1], p0[2], p0[3]};
    u2a.iv = (int4_){p0[4], p0[5], p0[6], p0[7]};
    u1b.iv = (int4_){p1[0], p1[1], p1[2], p1[3]};
    u2b.iv = (int4_){p1[4], p1[5], p1[6], p1[7]};

    d2_0 = MFMA32(vf1, u1a.sv, d2_0);
    d2_0 = MFMA32(vf2, u2a.sv, d2_0);
    d2_1 = MFMA32(vf1, u1b.sv, d2_1);
    d2_1 = MFMA32(vf2, u2b.sv, d2_1);
  }

  float loss = d2_0[0] * g0.x + d2_0[1] * g0.y + d2_0[2] * g0.z + d2_0[3] * g0.w
             + d2_1[0] * g1v.x + d2_1[1] * g1v.y + d2_1[2] * g1v.z + d2_1[3] * g1v.w;
  float r = blockReduceSum(loss);

  int blkflat = ((bb * JSP + jc) * IBLOCKS + ib);
  if (tid == 0) {
    pl[blkflat] = r;
    __threadfence();
    unsigned prev = atomicAdd(cnt_, 1u);
    isLast = (prev == NB - 1);
  }
  __syncthreads();
  if (isLast) {
    __threadfence();
    float v = 0.0f;
    for (int k = tid; k < NB; k += 256) v += pl[k];
    float rr = blockReduceSum(v);
    if (tid == 0) out[0] = rr;
  }
}

extern "C" void kernel_launch(void* const* d_in, const int* in_sizes, int n_in,
                              void* d_out, int out_size, void* d_ws, size_t ws_size,
                              hipStream_t stream) {
  const float* I = (const float*)d_in[0];
  const float* U = (const float*)d_in[1];
  float* out = (float*)d_out;

  char* w = (char*)d_ws;
  float* part = (float*)w;                  w += (size_t)B_ * JSP * NPTP * 4;
  unsigned short* Vt = (unsigned short*)w;  w += (size_t)B_ * 4 * NPTP * 2;
  float4* G4  = (float4*)w;                 w += (size_t)B_ * NPTP * 16;
  float*  pl  = (float*)w;                  w += (size_t)NB * 4;
  unsigned* cnt_ = (unsigned*)w;            w += 64;

  hipMemsetAsync(cnt_, 0, 4, stream);
  dim3 grid(IBLOCKS, JSP, B_);
  pass1_kernel<<<grid, 256, 0, stream>>>(I, part);
  finalize_kernel<<<(B_ * NPTP + 255) / 256, 256, 0, stream>>>(U, part, Vt, G4);
  pass2_kernel<<<grid, 256, 0, stream>>>(I, Vt, G4, pl, cnt_, out);
}